// Round 6
// baseline (63.863 us; speedup 1.0000x reference)
//
#include <hip/hip_runtime.h>
#include <hip/hip_bf16.h>
#include <math.h>

#define B_ 4
#define L_ 2048
#define H_ 8
#define E_ 64
#define HE 512   // H_*E_ : float stride between consecutive seq positions

typedef short bf16x8 __attribute__((ext_vector_type(8)));
typedef float f32x4 __attribute__((ext_vector_type(4)));
typedef float f32x16 __attribute__((ext_vector_type(16)));
typedef unsigned short u16x4 __attribute__((ext_vector_type(4)));
typedef unsigned short u16x8 __attribute__((ext_vector_type(8)));

__device__ __forceinline__ unsigned short f2b(float f) {
  return __builtin_bit_cast(unsigned short, (__hip_bfloat16)f);
}
__device__ __forceinline__ unsigned cvtpk(float lo, float hi) {
  unsigned r;
  asm("v_cvt_pk_bf16_f32 %0, %1, %2" : "=v"(r) : "v"(lo), "v"(hi));
  return r;
}
__device__ __forceinline__ void pl32swap(unsigned &a, unsigned &b) {
  asm volatile("v_permlane32_swap_b32 %0, %1" : "+v"(a), "+v"(b));
}

// Flash attention fwd, causal, tau-scaled.
// Block = 4 waves, 32 q-rows/wave (QBLK=128). KVBLK=128 (2 fused kv tiles
// per iteration): halves barriers/iterations, 4 independent QK MFMA chains.
// 32x32x16 MFMA, swapped QK^T (S^T = K Q^T -> lane-local softmax), P routed
// to PV A-frags via cvt_pk + permlane32_swap (T12), double-buffered LDS,
// T14 early loads, defer-max (T13), setprio (T5).
__global__ __launch_bounds__(256, 2) void attn_fwd(
    const float* __restrict__ Q, const float* __restrict__ K,
    const float* __restrict__ V, const float* __restrict__ tau,
    float* __restrict__ O)
{
  // balanced remap: CU c gets flat {c, c+256} -> qt {j, 15-j} (17 tile-units
  // each); (b,h) fixed per flat%32 -> all q-tiles of one (b,h) on one XCD.
  const int f  = blockIdx.x + 16 * (blockIdx.y + 8 * blockIdx.z);
  const int u  = f >> 5, hb = f & 31;
  const int h  = hb & 7, b = hb >> 3;
  const int qt = (u < 8) ? u : 23 - u;

  const int tid  = threadIdx.x;
  const int wave = tid >> 6, lane = tid & 63;
  const int l31 = lane & 31, hi = lane >> 5;
  const int l7 = l31 & 7;

  __shared__ unsigned short ldsK[2][128 * 64];   // [kv][e],  XOR-16B swizzle
  __shared__ unsigned short ldsV[2][64 * 128];   // [d][kv],  XOR-16B swizzle

  const float qscale = 0.125f * expf(tau[b]) * 1.44269504088896f;
  const int q0w = qt * 128 + wave * 32;          // wave's first q-row
  const int myq = q0w + l31;                     // lane's q (dup over hi)
  const int dqd = 32 * wave + l31;               // diagonal-tile bound

  // Q fragments (B operand): qf[ks][j] = Q[myq][16ks + 8hi + j]
  const float* Qb = Q + (((size_t)b * L_ + myq) * H_ + h) * E_;
  bf16x8 qf[4];
  #pragma unroll
  for (int ks = 0; ks < 4; ++ks) {
    f32x4 a = *(const f32x4*)(Qb + ks * 16 + hi * 8);
    f32x4 c = *(const f32x4*)(Qb + ks * 16 + hi * 8 + 4);
    #pragma unroll
    for (int j = 0; j < 4; ++j) {
      qf[ks][j]     = (short)f2b(a[j] * qscale);
      qf[ks][4 + j] = (short)f2b(c[j] * qscale);
    }
  }

  float m_run = -INFINITY, l_run = 0.0f;
  f32x16 oacc[2];
  #pragma unroll
  for (int nd = 0; nd < 2; ++nd)
    #pragma unroll
    for (int r = 0; r < 16; ++r) oacc[nd][r] = 0.0f;

  // ---- staging maps (256 threads, 2 halves of the 128-kv tile) ----
  // K: row = tid>>2 (+64), 16-float chunk (tid&3)*16 -> 2 u16x8/half
  // V: kv0 = (tid&15)*4 (+64), d0 = (tid>>4)*4 -> 4x4 transpose, 4 u16x4/half
  const int krow = tid >> 2, kcg = tid & 3;
  const int vkv = (tid & 15) * 4, vd = (tid >> 4) * 4;
  const float* Kp = K + ((size_t)b * L_ * H_ + h) * E_ + (size_t)krow * HE + kcg * 16;
  const float* Vp = V + ((size_t)b * L_ * H_ + h) * E_ + (size_t)vkv * HE + vd;

  const int nt = qt + 1;   // 128-kv tiles; every wave's diagonal is tile qt

  f32x4 kq[2][4], vq[2][4];
  // ---- prologue: load + stage tile 0 into buf 0 ----
  #pragma unroll
  for (int hf = 0; hf < 2; ++hf) {
    #pragma unroll
    for (int i = 0; i < 4; ++i) kq[hf][i] = *(const f32x4*)(Kp + hf * 64 * HE + 4 * i);
    #pragma unroll
    for (int i = 0; i < 4; ++i) vq[hf][i] = *(const f32x4*)(Vp + hf * 64 * HE + (size_t)i * HE);
  }
  #pragma unroll
  for (int hf = 0; hf < 2; ++hf) {
    const int r = krow + 64 * hf;
    u16x8 w0, w1;
    #pragma unroll
    for (int j = 0; j < 4; ++j) {
      w0[j] = f2b(kq[hf][0][j]); w0[4 + j] = f2b(kq[hf][1][j]);
      w1[j] = f2b(kq[hf][2][j]); w1[4 + j] = f2b(kq[hf][3][j]);
    }
    *(u16x8*)(&ldsK[0][r * 64 + (((2 * kcg) ^ (krow & 7)) << 3)]) = w0;
    *(u16x8*)(&ldsK[0][r * 64 + (((2 * kcg + 1) ^ (krow & 7)) << 3)]) = w1;
    #pragma unroll
    for (int jd = 0; jd < 4; ++jd) {
      const int row = vd + jd;
      u16x4 vw;
      #pragma unroll
      for (int i = 0; i < 4; ++i) vw[i] = f2b(vq[hf][i][jd]);
      *(u16x4*)(&ldsV[0][row * 128 + ((((vkv >> 3) + 8 * hf) ^ (row & 15)) << 3) + (vkv & 7)]) = vw;
    }
  }
  __syncthreads();
  int cur = 0;

  for (int t = 0; t < nt; ++t) {
    const bool havenext = (t + 1 < nt);
    if (havenext) {   // T14: issue next-tile loads early, LDS-write late
      const float* Kn = Kp + (size_t)(t + 1) * 128 * HE;
      const float* Vn = Vp + (size_t)(t + 1) * 128 * HE;
      #pragma unroll
      for (int hf = 0; hf < 2; ++hf) {
        #pragma unroll
        for (int i = 0; i < 4; ++i) kq[hf][i] = *(const f32x4*)(Kn + hf * 64 * HE + 4 * i);
        #pragma unroll
        for (int i = 0; i < 4; ++i) vq[hf][i] = *(const f32x4*)(Vn + hf * 64 * HE + (size_t)i * HE);
      }
    }

    const unsigned short* Kl = ldsK[cur];
    const unsigned short* Vl = ldsV[cur];

    // ---- S^T = K Q^T : 16 MFMAs, 4 independent chains ----
    f32x16 sacc[4];
    #pragma unroll
    for (int mt = 0; mt < 4; ++mt)
      #pragma unroll
      for (int r = 0; r < 16; ++r) sacc[mt][r] = 0.0f;
    __builtin_amdgcn_s_setprio(1);
    #pragma unroll
    for (int ks = 0; ks < 4; ++ks) {
      #pragma unroll
      for (int mt = 0; mt < 4; ++mt) {
        bf16x8 kf = *(const bf16x8*)(Kl + (32 * mt + l31) * 64 +
                                     (((2 * ks + hi) ^ l7) << 3));
        sacc[mt] = __builtin_amdgcn_mfma_f32_32x32x16_bf16(kf, qf[ks], sacc[mt], 0, 0, 0);
      }
    }
    __builtin_amdgcn_s_setprio(0);

    // ---- causal mask (diagonal tile only; dqd is loop-invariant) ----
    if (t == nt - 1) {
      #pragma unroll
      for (int mt = 0; mt < 4; ++mt)
        #pragma unroll
        for (int r = 0; r < 16; ++r) {
          const int kvl = 32 * mt + (r & 3) + 8 * (r >> 2) + 4 * hi;
          if (kvl > dqd) sacc[mt][r] = -3.0e38f;
        }
    }

    // ---- online softmax over 128 kv: max tree + defer-max (T13) ----
    float p0 = sacc[0][0], p1 = sacc[0][1], p2 = sacc[0][2], p3 = sacc[0][3];
    #pragma unroll
    for (int mt = 0; mt < 4; ++mt)
      #pragma unroll
      for (int r = (mt == 0 ? 4 : 0); r < 16; r += 4) {
        p0 = fmaxf(p0, sacc[mt][r]);
        p1 = fmaxf(p1, sacc[mt][r + 1]);
        p2 = fmaxf(p2, sacc[mt][r + 2]);
        p3 = fmaxf(p3, sacc[mt][r + 3]);
      }
    float mx = fmaxf(fmaxf(p0, p1), fmaxf(p2, p3));
    mx = fmaxf(mx, __shfl_xor(mx, 32));

    if (!__all(mx - m_run <= 8.0f)) {      // rescale needed (rare)
      const float mnew = fmaxf(m_run, mx);
      const float corr = exp2f(m_run - mnew);   // tile 0: exp2(-inf)=0
      m_run = mnew;
      l_run *= corr;
      #pragma unroll
      for (int r = 0; r < 16; ++r) {
        const int qrow = (r & 3) + 8 * (r >> 2) + 4 * hi;
        const float cr = __shfl(corr, qrow);
        oacc[0][r] *= cr;
        oacc[1][r] *= cr;
      }
    }

    float s0 = 0.f, s1 = 0.f, s2 = 0.f, s3 = 0.f;
    #pragma unroll
    for (int mt = 0; mt < 4; ++mt)
      #pragma unroll
      for (int r = 0; r < 16; r += 4) {
        float e0 = exp2f(sacc[mt][r]     - m_run);
        float e1 = exp2f(sacc[mt][r + 1] - m_run);
        float e2 = exp2f(sacc[mt][r + 2] - m_run);
        float e3 = exp2f(sacc[mt][r + 3] - m_run);
        sacc[mt][r] = e0; sacc[mt][r + 1] = e1;
        sacc[mt][r + 2] = e2; sacc[mt][r + 3] = e3;
        s0 += e0; s1 += e1; s2 += e2; s3 += e3;
      }
    float rs = (s0 + s1) + (s2 + s3);
    rs += __shfl_xor(rs, 32);
    l_run += rs;

    // ---- P -> bf16 packed words (per 32-kv subtile, T12 step 1) ----
    unsigned pk[4][8];
    #pragma unroll
    for (int mt = 0; mt < 4; ++mt)
      #pragma unroll
      for (int i = 0; i < 8; ++i)
        pk[mt][i] = cvtpk(sacc[mt][2 * i], sacc[mt][2 * i + 1]);

    // ---- O += P V : 16 MFMAs; pf via permlane32_swap (T12 step 2) ----
    __builtin_amdgcn_s_setprio(1);
    #pragma unroll
    for (int ks = 0; ks < 8; ++ks) {
      const int c = ks & 1;
      unsigned a  = pk[ks >> 1][4 * c];
      unsigned y  = pk[ks >> 1][4 * c + 2];
      unsigned a2 = pk[ks >> 1][4 * c + 1];
      unsigned y2 = pk[ks >> 1][4 * c + 3];
      pl32swap(a, y);
      pl32swap(a2, y2);
      union { unsigned w[4]; bf16x8 v; } pu;
      pu.w[0] = a; pu.w[1] = a2; pu.w[2] = y; pu.w[3] = y2;
      #pragma unroll
      for (int nd = 0; nd < 2; ++nd) {
        const int d = 32 * nd + l31;
        bf16x8 vf = *(const bf16x8*)(Vl + d * 128 +
                                     (((2 * ks + hi) ^ (d & 15)) << 3));
        oacc[nd] = __builtin_amdgcn_mfma_f32_32x32x16_bf16(pu.v, vf, oacc[nd], 0, 0, 0);
      }
    }
    __builtin_amdgcn_s_setprio(0);

    if (havenext) {
      const int nb = cur ^ 1;
      #pragma unroll
      for (int hf = 0; hf < 2; ++hf) {
        const int r = krow + 64 * hf;
        u16x8 w0, w1;
        #pragma unroll
        for (int j = 0; j < 4; ++j) {
          w0[j] = f2b(kq[hf][0][j]); w0[4 + j] = f2b(kq[hf][1][j]);
          w1[j] = f2b(kq[hf][2][j]); w1[4 + j] = f2b(kq[hf][3][j]);
        }
        *(u16x8*)(&ldsK[nb][r * 64 + (((2 * kcg) ^ (krow & 7)) << 3)]) = w0;
        *(u16x8*)(&ldsK[nb][r * 64 + (((2 * kcg + 1) ^ (krow & 7)) << 3)]) = w1;
        #pragma unroll
        for (int jd = 0; jd < 4; ++jd) {
          const int row = vd + jd;
          u16x4 vw;
          #pragma unroll
          for (int i = 0; i < 4; ++i) vw[i] = f2b(vq[hf][i][jd]);
          *(u16x4*)(&ldsV[nb][row * 128 + ((((vkv >> 3) + 8 * hf) ^ (row & 15)) << 3) + (vkv & 7)]) = vw;
        }
      }
      __syncthreads();
      cur = nb;
    }
  }

  // ---- epilogue: normalize and store f32 ----
  const float linv = 1.0f / l_run;
  float* Ob = O + (((size_t)b * L_ + q0w) * H_ + h) * E_;
  #pragma unroll
  for (int r = 0; r < 16; ++r) {
    const int qrow = (r & 3) + 8 * (r >> 2) + 4 * hi;
    const float inv = __shfl(linv, qrow);
    Ob[(size_t)qrow * HE + l31]      = oacc[0][r] * inv;
    Ob[(size_t)qrow * HE + 32 + l31] = oacc[1][r] * inv;
  }
}

extern "C" void kernel_launch(void* const* d_in, const int* in_sizes, int n_in,
                              void* d_out, int out_size, void* d_ws, size_t ws_size,
                              hipStream_t stream) {
  (void)in_sizes; (void)n_in; (void)out_size; (void)d_ws; (void)ws_size;
  const float* Q   = (const float*)d_in[0];
  const float* K   = (const float*)d_in[1];
  const float* V   = (const float*)d_in[2];
  // d_in[3] = attn_mask: ignored, causality applied analytically.
  const float* tau = (const float*)d_in[4];
  float* O = (float*)d_out;
  dim3 grid(L_ / 128, H_, B_), block(256);
  hipLaunchKernelGGL(attn_fwd, grid, block, 0, stream, Q, K, V, tau, O);
}